// Round 11
// baseline (600.954 us; speedup 1.0000x reference)
//
#include <hip/hip_runtime.h>
#include <stdint.h>

#define NT 16384       // total nodes (8 * 2048)
#define NN 2048
#define NB 8
#define NBKT 16        // source buckets of 1024 nodes

typedef __attribute__((ext_vector_type(4))) float f32x4;
typedef __attribute__((ext_vector_type(8))) short s16x8;
typedef __attribute__((ext_vector_type(4))) short s16x4;

__device__ __forceinline__ float bf2f(short u) {
    unsigned v = ((unsigned)(unsigned short)u) << 16;
    return __builtin_bit_cast(float, v);
}
__device__ __forceinline__ short f2bf(float f) {
    unsigned u = __builtin_bit_cast(unsigned, f);
    u += 0x7fffu + ((u >> 16) & 1u);
    return (short)(u >> 16);
}
__device__ __forceinline__ void gload16(const void* g, void* l) {
    __builtin_amdgcn_global_load_lds(
        (const __attribute__((address_space(1))) void*)g,
        (__attribute__((address_space(3))) void*)l, 16, 0, 0);
}
__device__ __forceinline__ long long eidx(const void* ei, long long i, int is64) {
    if (is64) return ((const long long*)ei)[i];
    return (long long)((const int*)ei)[i];
}

// ---- init: blocks 0..63 zero cnt16; block 64 detects int64 vs int32 ----
__global__ void k_init(const void* ei, int* flag, int* cnt16) {
    if (blockIdx.x == 64) {
        __shared__ int bad;
        if (threadIdx.x == 0) bad = 0;
        __syncthreads();
        const long long* p = (const long long*)ei;
        for (int i = threadIdx.x; i < 2048; i += 256) {
            long long v = p[i];
            if (v < 0 || v >= NT) bad = 1;
        }
        __syncthreads();
        if (threadIdx.x == 0) *flag = bad ? 0 : 1;
    } else {
        int base = blockIdx.x * 4096 + threadIdx.x;
#pragma unroll
        for (int q = 0; q < 16; q++) cnt16[base + q * 256] = 0;
    }
}

// ---- fused: per-(target,bucket) counts (blocks < nEB) + weight converts ----
__global__ void k_count16(const void* ei, int E, int nEB, const int* flag, int* cnt16,
                          const float* __restrict__ W1, const float* __restrict__ W2,
                          const float* __restrict__ W3, short* __restrict__ Wt1,
                          short* __restrict__ Wt2, short* __restrict__ Wt3) {
    if ((int)blockIdx.x < nEB) {
        int e = blockIdx.x * 256 + threadIdx.x;
        if (e >= E) return;
        int f = *flag;
        int r = (int)eidx(ei, e, f);
        int c = (int)eidx(ei, (long long)E + e, f);
        atomicAdd(&cnt16[c * NBKT + (r >> 10)], 1);
    } else {
        int idx = (blockIdx.x - nEB) * 256 + threadIdx.x;
        const float* W; short* Wt; int N, base;
        if (idx < 262144)      { W = W1; Wt = Wt1; N = 512; base = idx; }
        else if (idx < 524288) { W = W2; Wt = Wt2; N = 512; base = idx - 262144; }
        else                   { W = W3; Wt = Wt3; N = 256; base = idx - 524288; }
        int k = base / N, n = base - k * N;
        Wt[(size_t)n * 512 + k] = f2bf(W[base]);
    }
}

// ---- fused deg + scan + bcur: one block, 1024 threads x 16 nodes ----
__global__ __launch_bounds__(1024) void k_scanall(const int* __restrict__ cnt16,
        int* __restrict__ deg, int* __restrict__ offs, float* __restrict__ dinv,
        int* __restrict__ bcur) {
    __shared__ int ps[1024];
    const int t = threadIdx.x;
    const int base = t * 16;
    int degloc[16];
    int s = 0;
#pragma unroll
    for (int j = 0; j < 16; j++) {
        const int* p = cnt16 + (base + j) * NBKT;
        int d = 0;
#pragma unroll
        for (int b = 0; b < NBKT; b++) d += p[b];
        degloc[j] = d;
        s += d;
    }
    ps[t] = s;
    __syncthreads();
    for (int o = 1; o < 1024; o <<= 1) {
        int v = (t >= o) ? ps[t - o] : 0;
        __syncthreads();
        ps[t] += v;
        __syncthreads();
    }
    int ex = ps[t] - s;   // exclusive prefix over nodes
#pragma unroll
    for (int j = 0; j < 16; j++) {
        const int node = base + j;
        deg[node]  = degloc[j];
        offs[node] = ex;
        dinv[node] = rsqrtf((float)(degloc[j] + 1));   // +1 self loop
        int run = ex;
        const int* p = cnt16 + node * NBKT;
#pragma unroll
        for (int b = 0; b < NBKT; b++) {
            bcur[node * NBKT + b] = run;
            run += p[b];
        }
        ex += degloc[j];
    }
}

// ---- fused: bucket-ordered CSR fill (blocks < nEB) + x scale ----
__global__ void k_fill16(const void* ei, int E, int nEB, const int* flag,
                         int* bcur, int* csr,
                         const float* __restrict__ x, const float* __restrict__ dinv,
                         short* __restrict__ xs) {
    if ((int)blockIdx.x < nEB) {
        int e = blockIdx.x * 256 + threadIdx.x;
        if (e >= E) return;
        int f = *flag;
        int r = (int)eidx(ei, e, f);
        int c = (int)eidx(ei, (long long)E + e, f);
        int pos = atomicAdd(&bcur[c * NBKT + (r >> 10)], 1);
        csr[pos] = r;
    } else {
        int i = (blockIdx.x - nEB) * 256 + threadIdx.x;   // group of 4 floats
        f32x4 v = *(const f32x4*)(x + (size_t)i * 4);
        float d = dinv[i >> 7];
        s16x4 o;
#pragma unroll
        for (int j = 0; j < 4; j++) o[j] = f2bf(v[j] * d);
        *(s16x4*)(xs + (size_t)i * 4) = o;
    }
}

// ---- bf16 GEMM: 64x128 tile, BK=64, T2 XOR-swizzle ----
__global__ __launch_bounds__(256, 4) void k_gemm(const short* __restrict__ A,
        const short* __restrict__ Bt, short* __restrict__ Co, int N, int K) {
    __shared__ short As[64 * 64];
    __shared__ short Bs[128 * 64];
    const int t = threadIdx.x;
    const int w = t >> 6, l = t & 63;
    const int row0 = blockIdx.x * 64;
    const int col0 = blockIdx.y * 128;
    const int lr = l & 15, lhi = l >> 4;
    const int wc = w * 32;
    f32x4 acc[4][2] = {};
    int arow[2], ajs[2], brow[4], bjs[4];
#pragma unroll
    for (int i = 0; i < 2; i++) {
        int s = t + i * 256;
        arow[i] = s >> 3; ajs[i] = (s & 7) ^ (arow[i] & 7);
    }
#pragma unroll
    for (int i = 0; i < 4; i++) {
        int s = t + i * 256;
        brow[i] = s >> 3; bjs[i] = (s & 7) ^ (brow[i] & 7);
    }
    int aoff[2][4], boff[2][2];
#pragma unroll
    for (int kk = 0; kk < 2; kk++) {
#pragma unroll
        for (int m = 0; m < 4; m++) {
            int ar = m * 16 + lr;
            aoff[kk][m] = ar * 64 + (((kk * 4 + lhi) ^ (ar & 7)) << 3);
        }
#pragma unroll
        for (int n = 0; n < 2; n++) {
            int br = wc + n * 16 + lr;
            boff[kk][n] = br * 64 + (((kk * 4 + lhi) ^ (br & 7)) << 3);
        }
    }
    for (int k0 = 0; k0 < K; k0 += 64) {
#pragma unroll
        for (int i = 0; i < 2; i++)
            gload16(A + (size_t)(row0 + arow[i]) * K + k0 + ajs[i] * 8,
                    (void*)(As + (t + i * 256) * 8));
#pragma unroll
        for (int i = 0; i < 4; i++)
            gload16(Bt + (size_t)(col0 + brow[i]) * K + k0 + bjs[i] * 8,
                    (void*)(Bs + (t + i * 256) * 8));
        __syncthreads();
#pragma unroll
        for (int kk = 0; kk < 2; kk++) {
            s16x8 af[4], bfr[2];
#pragma unroll
            for (int m = 0; m < 4; m++) af[m]  = *(const s16x8*)(As + aoff[kk][m]);
#pragma unroll
            for (int n = 0; n < 2; n++) bfr[n] = *(const s16x8*)(Bs + boff[kk][n]);
#pragma unroll
            for (int m = 0; m < 4; m++)
#pragma unroll
                for (int n = 0; n < 2; n++)
                    acc[m][n] = __builtin_amdgcn_mfma_f32_16x16x32_bf16(af[m], bfr[n], acc[m][n], 0, 0, 0);
        }
        __syncthreads();
    }
#pragma unroll
    for (int m = 0; m < 4; m++)
#pragma unroll
        for (int n = 0; n < 2; n++)
#pragma unroll
            for (int j = 0; j < 4; j++) {
                int r = row0 + m * 16 + lhi * 4 + j;
                int c = col0 + wc + n * 16 + lr;
                Co[(size_t)r * N + c] = f2bf(acc[m][n][j]);
            }
}

// ---- aggregation, C=512 ----
__global__ __launch_bounds__(256) void k_agg512(const short* __restrict__ T,
        const int* __restrict__ offs, const int* __restrict__ cnt,
        const int* __restrict__ csr, const float* __restrict__ dinv,
        const float* __restrict__ bias, short* __restrict__ H) {
    const int w = threadIdx.x >> 6, l = threadIdx.x & 63;
    const int node = blockIdx.x * 4 + w;
    const int c0 = l * 8;
    const short* base = T + c0;
    float acc[8];
    {
        s16x8 r = *(const s16x8*)(base + (size_t)node * 512);
#pragma unroll
        for (int v = 0; v < 8; v++) acc[v] = bf2f(r[v]);
    }
    const int beg = offs[node], end = beg + cnt[node];
    int j = beg;
    for (; j + 8 <= end; j += 8) {
        int sIx[8];
#pragma unroll
        for (int q = 0; q < 8; q++) sIx[q] = csr[j + q];
        s16x8 r[8];
#pragma unroll
        for (int q = 0; q < 8; q++) r[q] = *(const s16x8*)(base + (size_t)sIx[q] * 512);
#pragma unroll
        for (int v = 0; v < 8; v++) {
            float s01 = bf2f(r[0][v]) + bf2f(r[1][v]);
            float s23 = bf2f(r[2][v]) + bf2f(r[3][v]);
            float s45 = bf2f(r[4][v]) + bf2f(r[5][v]);
            float s67 = bf2f(r[6][v]) + bf2f(r[7][v]);
            acc[v] += (s01 + s23) + (s45 + s67);
        }
    }
    for (; j + 2 <= end; j += 2) {
        int s0 = csr[j], s1 = csr[j + 1];
        s16x8 r0 = *(const s16x8*)(base + (size_t)s0 * 512);
        s16x8 r1 = *(const s16x8*)(base + (size_t)s1 * 512);
#pragma unroll
        for (int v = 0; v < 8; v++) acc[v] += bf2f(r0[v]) + bf2f(r1[v]);
    }
    for (; j < end; j++) {
        s16x8 r0 = *(const s16x8*)(base + (size_t)csr[j] * 512);
#pragma unroll
        for (int v = 0; v < 8; v++) acc[v] += bf2f(r0[v]);
    }
    const float dc = dinv[node];
    f32x4 b0 = *(const f32x4*)(bias + c0);
    f32x4 b1 = *(const f32x4*)(bias + c0 + 4);
    s16x8 outv;
#pragma unroll
    for (int v = 0; v < 8; v++) {
        float bb = (v < 4) ? b0[v] : b1[v - 4];
        float o = acc[v] * dc + bb;
        o = fmaxf(o, 0.f);
        o *= dc;
        outv[v] = f2bf(o);
    }
    *(s16x8*)(H + (size_t)node * 512 + c0) = outv;
}

// ---- FUSED encoder: agg256 -> hB, then part = hB @ We-slice ----
__global__ __launch_bounds__(256) void k_enc(const short* __restrict__ T,
        const int* __restrict__ offs, const int* __restrict__ cnt,
        const int* __restrict__ csr, const float* __restrict__ dinv,
        const float* __restrict__ b3, const float* __restrict__ We,
        float* __restrict__ part) {
    __shared__ float hB[8 * 512];
    __shared__ float red[32 * 128];
    const int t = threadIdx.x;
    const int w = t >> 6, l = t & 63;
    const int ln0 = blockIdx.x * 2;
    const int c0 = l * 4;
    const short* base = T + c0;
    f32x4 bb = *(const f32x4*)(b3 + c0);
    for (int p = 0; p < 4; p++) {
        const int i = w * 4 + p;
        const int b = i >> 1, lnk = i & 1;
        const int node = b * NN + ln0 + lnk;
        float acc[4];
        {
            s16x4 r = *(const s16x4*)(base + (size_t)node * 256);
#pragma unroll
            for (int v = 0; v < 4; v++) acc[v] = bf2f(r[v]);
        }
        const int beg = offs[node], end = beg + cnt[node];
        int j = beg;
        for (; j + 8 <= end; j += 8) {
            int sIx[8];
#pragma unroll
            for (int q = 0; q < 8; q++) sIx[q] = csr[j + q];
            s16x4 r[8];
#pragma unroll
            for (int q = 0; q < 8; q++) r[q] = *(const s16x4*)(base + (size_t)sIx[q] * 256);
#pragma unroll
            for (int v = 0; v < 4; v++) {
                float s01 = bf2f(r[0][v]) + bf2f(r[1][v]);
                float s23 = bf2f(r[2][v]) + bf2f(r[3][v]);
                float s45 = bf2f(r[4][v]) + bf2f(r[5][v]);
                float s67 = bf2f(r[6][v]) + bf2f(r[7][v]);
                acc[v] += (s01 + s23) + (s45 + s67);
            }
        }
        for (; j < end; j++) {
            s16x4 r0 = *(const s16x4*)(base + (size_t)csr[j] * 256);
#pragma unroll
            for (int v = 0; v < 4; v++) acc[v] += bf2f(r0[v]);
        }
        const float dc = dinv[node];
        f32x4 o;
#pragma unroll
        for (int v = 0; v < 4; v++) o[v] = acc[v] * dc + bb[v];
        *(f32x4*)(&hB[b * 512 + lnk * 256 + c0]) = o;
    }
    __syncthreads();
    const int col = (t & 127) * 4;
    const int khalf = t >> 7;
    float acc[8][4] = {};
    const float* wp = We + (size_t)(blockIdx.x * 512 + khalf * 256) * 512 + col;
    const float* hp = hB + khalf * 256;
#pragma unroll 2
    for (int k = 0; k < 256; k++) {
        f32x4 wv = *(const f32x4*)(wp + (size_t)k * 512);
        float h0 = hp[k],        h1 = hp[512 + k],  h2 = hp[1024 + k], h3v = hp[1536 + k];
        float h4 = hp[2048 + k], h5 = hp[2560 + k], h6 = hp[3072 + k], h7 = hp[3584 + k];
#pragma unroll
        for (int c = 0; c < 4; c++) {
            acc[0][c] += h0 * wv[c];
            acc[1][c] += h1 * wv[c];
            acc[2][c] += h2 * wv[c];
            acc[3][c] += h3v * wv[c];
            acc[4][c] += h4 * wv[c];
            acc[5][c] += h5 * wv[c];
            acc[6][c] += h6 * wv[c];
            acc[7][c] += h7 * wv[c];
        }
    }
    if (khalf) {
#pragma unroll
        for (int b = 0; b < 8; b++)
#pragma unroll
            for (int c = 0; c < 4; c++)
                red[(b * 4 + c) * 128 + (t - 128)] = acc[b][c];
    }
    __syncthreads();
    if (!khalf) {
#pragma unroll
        for (int b = 0; b < 8; b++) {
            f32x4 o;
#pragma unroll
            for (int c = 0; c < 4; c++) o[c] = acc[b][c] + red[(b * 4 + c) * 128 + t];
            *(f32x4*)(part + (size_t)blockIdx.x * 4096 + b * 512 + col) = o;
        }
    }
}

// ---- encoder stage 2 ----
__global__ __launch_bounds__(256) void k_zred(const float* __restrict__ part,
                                              float* __restrict__ zpart) {
    const int n = blockIdx.x * 256 + threadIdx.x;
    const int p0 = blockIdx.y * 128;
    float s = 0.f;
    for (int q = 0; q < 128; q++) s += part[(size_t)(p0 + q) * 4096 + n];
    zpart[(size_t)blockIdx.y * 4096 + n] = s;
}

// ---- decoder ----
__global__ __launch_bounds__(256) void k_dec(const float* __restrict__ zpart,
        const float* __restrict__ be, const float* __restrict__ Wd,
        const float* __restrict__ bd, float* __restrict__ out) {
    __shared__ float zs[512];
    const int b = blockIdx.x >> 3;
    const int n = ((blockIdx.x & 7) << 8) + threadIdx.x;
    for (int i = threadIdx.x; i < 512; i += 256) {
        float s = be[i];
#pragma unroll
        for (int p = 0; p < 8; p++) s += zpart[(size_t)p * 4096 + b * 512 + i];
        zs[i] = s;
    }
    __syncthreads();
    float acc = bd[n];
    for (int k = 0; k < 512; k++) acc += zs[k] * Wd[(size_t)k * 2048 + n];
    out[b * 2048 + n] = acc;
}

extern "C" void kernel_launch(void* const* d_in, const int* in_sizes, int n_in,
                              void* d_out, int out_size, void* d_ws, size_t ws_size,
                              hipStream_t stream) {
    const float* x  = (const float*)d_in[0];
    const void*  ei = d_in[1];
    const float* W1 = (const float*)d_in[4];
    const float* b1 = (const float*)d_in[5];
    const float* W2 = (const float*)d_in[6];
    const float* b2 = (const float*)d_in[7];
    const float* W3 = (const float*)d_in[8];
    const float* b3 = (const float*)d_in[9];
    const float* We = (const float*)d_in[10];
    const float* be = (const float*)d_in[11];
    const float* Wd = (const float*)d_in[12];
    const float* bd = (const float*)d_in[13];
    float* out = (float*)d_out;
    const int E = in_sizes[1] / 2;
    const int nEB = (E + 255) / 256;

    char* ws = (char*)d_ws;
    size_t off = 0;
    auto alloc = [&](size_t bytes) {
        void* p = ws + off;
        off = (off + bytes + 255) & ~(size_t)255;
        return p;
    };
    int*   flag   = (int*)  alloc(4);
    int*   deg    = (int*)  alloc((size_t)NT * 4);
    int*   offs   = (int*)  alloc((size_t)NT * 4);
    float* dinv   = (float*)alloc((size_t)NT * 4);
    int*   csr    = (int*)  alloc((size_t)E * 4);
    short* Wt1    = (short*)alloc((size_t)512 * 512 * 2);
    short* Wt2    = (short*)alloc((size_t)512 * 512 * 2);
    short* Wt3    = (short*)alloc((size_t)256 * 512 * 2);
    short* bufA   = (short*)alloc((size_t)NT * 512 * 2);
    short* bufB   = (short*)alloc((size_t)NT * 512 * 2);
    float* part   = (float*)alloc((size_t)1024 * 4096 * 4);
    float* zpart  = (float*)alloc((size_t)8 * 4096 * 4);
    // CSR-build temporaries alias into part (dead until k_enc writes it).
    int*   cnt16  = (int*)part;
    int*   bcur   = ((int*)part) + NT * NBKT;

    k_init<<<65, 256, 0, stream>>>(ei, flag, cnt16);
    k_count16<<<nEB + 2560, 256, 0, stream>>>(ei, E, nEB, flag, cnt16,
                                              W1, W2, W3, Wt1, Wt2, Wt3);
    k_scanall<<<1, 1024, 0, stream>>>(cnt16, deg, offs, dinv, bcur);
    k_fill16<<<nEB + 8192, 256, 0, stream>>>(ei, E, nEB, flag, bcur, csr, x, dinv, bufA);

    dim3 g1(256, 4);
    k_gemm<<<g1, 256, 0, stream>>>(bufA, Wt1, bufB, 512, 512);
    k_agg512<<<NT / 4, 256, 0, stream>>>(bufB, offs, deg, csr, dinv, b1, bufA);
    k_gemm<<<g1, 256, 0, stream>>>(bufA, Wt2, bufB, 512, 512);
    k_agg512<<<NT / 4, 256, 0, stream>>>(bufB, offs, deg, csr, dinv, b2, bufA);
    dim3 g3(256, 2);
    k_gemm<<<g3, 256, 0, stream>>>(bufA, Wt3, bufB, 256, 512);

    k_enc<<<1024, 256, 0, stream>>>(bufB, offs, deg, csr, dinv, b3, We, part);
    dim3 gz(16, 8);
    k_zred<<<gz, 256, 0, stream>>>(part, zpart);
    k_dec<<<64, 256, 0, stream>>>(zpart, be, Wd, bd, out);
}

// Round 12
// 485.041 us; speedup vs baseline: 1.2390x; 1.2390x over previous
//
#include <hip/hip_runtime.h>
#include <stdint.h>

#define NT 16384       // total nodes (8 * 2048)
#define NN 2048
#define NB 8
#define NBKT 16        // source buckets of 1024 nodes

typedef __attribute__((ext_vector_type(4))) float f32x4;
typedef __attribute__((ext_vector_type(8))) short s16x8;
typedef __attribute__((ext_vector_type(4))) short s16x4;

__device__ __forceinline__ float bf2f(short u) {
    unsigned v = ((unsigned)(unsigned short)u) << 16;
    return __builtin_bit_cast(float, v);
}
__device__ __forceinline__ short f2bf(float f) {
    unsigned u = __builtin_bit_cast(unsigned, f);
    u += 0x7fffu + ((u >> 16) & 1u);
    return (short)(u >> 16);
}
__device__ __forceinline__ void gload16(const void* g, void* l) {
    __builtin_amdgcn_global_load_lds(
        (const __attribute__((address_space(1))) void*)g,
        (__attribute__((address_space(3))) void*)l, 16, 0, 0);
}
__device__ __forceinline__ long long eidx(const void* ei, long long i, int is64) {
    if (is64) return ((const long long*)ei)[i];
    return (long long)((const int*)ei)[i];
}

// ---- init: blocks 0..63 zero cnt16; block 64 detects int64 vs int32 ----
__global__ void k_init(const void* ei, int* flag, int* cnt16) {
    if (blockIdx.x == 64) {
        __shared__ int bad;
        if (threadIdx.x == 0) bad = 0;
        __syncthreads();
        const long long* p = (const long long*)ei;
        for (int i = threadIdx.x; i < 2048; i += 256) {
            long long v = p[i];
            if (v < 0 || v >= NT) bad = 1;
        }
        __syncthreads();
        if (threadIdx.x == 0) *flag = bad ? 0 : 1;
    } else {
        int base = blockIdx.x * 4096 + threadIdx.x;
#pragma unroll
        for (int q = 0; q < 16; q++) cnt16[base + q * 256] = 0;
    }
}

// ---- per-(target, source-bucket) counts ----
__global__ void k_count16(const void* ei, int E, const int* flag, int* cnt16) {
    int e = blockIdx.x * 256 + threadIdx.x;
    if (e >= E) return;
    int f = *flag;
    int r = (int)eidx(ei, e, f);
    int c = (int)eidx(ei, (long long)E + e, f);
    atomicAdd(&cnt16[c * NBKT + (r >> 10)], 1);
}

// ---- deg[n] = sum over buckets ----
__global__ void k_deg(const int* __restrict__ cnt16, int* __restrict__ deg) {
    int n = blockIdx.x * 256 + threadIdx.x;
    const int* p = cnt16 + n * NBKT;
    int s = 0;
#pragma unroll
    for (int j = 0; j < NBKT; j++) s += p[j];
    deg[n] = s;
}

__global__ __launch_bounds__(1024) void k_scan(const int* __restrict__ count,
        int* __restrict__ offs, float* __restrict__ dinv) {
    __shared__ int ps[1024];
    const int t = threadIdx.x;
    const int base = t * 16;
    int loc[16];
    int s = 0;
#pragma unroll
    for (int j = 0; j < 16; j++) { loc[j] = count[base + j]; s += loc[j]; }
    ps[t] = s;
    __syncthreads();
    for (int o = 1; o < 1024; o <<= 1) {
        int v = (t >= o) ? ps[t - o] : 0;
        __syncthreads();
        ps[t] += v;
        __syncthreads();
    }
    int ex = ps[t] - s;   // exclusive prefix
#pragma unroll
    for (int j = 0; j < 16; j++) {
        offs[base + j] = ex;
        ex += loc[j];
        dinv[base + j] = rsqrtf((float)(loc[j] + 1));   // +1 self loop
    }
}

// ---- per-(node,bucket) fill cursors ----
__global__ void k_bcur(const int* __restrict__ cnt16, const int* __restrict__ offs,
                       int* __restrict__ bcur) {
    int n = blockIdx.x * 256 + threadIdx.x;
    int running = offs[n];
#pragma unroll
    for (int b = 0; b < NBKT; b++) {
        bcur[n * NBKT + b] = running;
        running += cnt16[n * NBKT + b];
    }
}

// ---- bucket-ordered CSR fill ----
__global__ void k_fill16(const void* ei, int E, const int* flag,
                         int* bcur, int* csr) {
    int e = blockIdx.x * 256 + threadIdx.x;
    if (e >= E) return;
    int f = *flag;
    int r = (int)eidx(ei, e, f);
    int c = (int)eidx(ei, (long long)E + e, f);
    int pos = atomicAdd(&bcur[c * NBKT + (r >> 10)], 1);
    csr[pos] = r;
}

// ---- fused: weight converts (blocks >= 8192) + x scale (blocks < 8192) ----
__global__ void k_convscale(const float* __restrict__ W1, const float* __restrict__ W2,
                            const float* __restrict__ W3, short* __restrict__ Wt1,
                            short* __restrict__ Wt2, short* __restrict__ Wt3,
                            const float* __restrict__ x, const float* __restrict__ dinv,
                            short* __restrict__ xs) {
    if (blockIdx.x < 8192) {
        int i = blockIdx.x * 256 + threadIdx.x;   // group of 4 floats
        f32x4 v = *(const f32x4*)(x + (size_t)i * 4);
        float d = dinv[i >> 7];
        s16x4 o;
#pragma unroll
        for (int j = 0; j < 4; j++) o[j] = f2bf(v[j] * d);
        *(s16x4*)(xs + (size_t)i * 4) = o;
    } else {
        int idx = (blockIdx.x - 8192) * 256 + threadIdx.x;
        const float* W; short* Wt; int N, base;
        if (idx < 262144)      { W = W1; Wt = Wt1; N = 512; base = idx; }
        else if (idx < 524288) { W = W2; Wt = Wt2; N = 512; base = idx - 262144; }
        else                   { W = W3; Wt = Wt3; N = 256; base = idx - 524288; }
        int k = base / N, n = base - k * N;
        Wt[(size_t)n * 512 + k] = f2bf(W[base]);
    }
}

// ---- bf16 GEMM: 64x128 tile, BK=64, T2 XOR-swizzle ----
__global__ __launch_bounds__(256, 4) void k_gemm(const short* __restrict__ A,
        const short* __restrict__ Bt, short* __restrict__ Co, int N, int K) {
    __shared__ short As[64 * 64];
    __shared__ short Bs[128 * 64];
    const int t = threadIdx.x;
    const int w = t >> 6, l = t & 63;
    const int row0 = blockIdx.x * 64;
    const int col0 = blockIdx.y * 128;
    const int lr = l & 15, lhi = l >> 4;
    const int wc = w * 32;
    f32x4 acc[4][2] = {};
    int arow[2], ajs[2], brow[4], bjs[4];
#pragma unroll
    for (int i = 0; i < 2; i++) {
        int s = t + i * 256;
        arow[i] = s >> 3; ajs[i] = (s & 7) ^ (arow[i] & 7);
    }
#pragma unroll
    for (int i = 0; i < 4; i++) {
        int s = t + i * 256;
        brow[i] = s >> 3; bjs[i] = (s & 7) ^ (brow[i] & 7);
    }
    int aoff[2][4], boff[2][2];
#pragma unroll
    for (int kk = 0; kk < 2; kk++) {
#pragma unroll
        for (int m = 0; m < 4; m++) {
            int ar = m * 16 + lr;
            aoff[kk][m] = ar * 64 + (((kk * 4 + lhi) ^ (ar & 7)) << 3);
        }
#pragma unroll
        for (int n = 0; n < 2; n++) {
            int br = wc + n * 16 + lr;
            boff[kk][n] = br * 64 + (((kk * 4 + lhi) ^ (br & 7)) << 3);
        }
    }
    for (int k0 = 0; k0 < K; k0 += 64) {
#pragma unroll
        for (int i = 0; i < 2; i++)
            gload16(A + (size_t)(row0 + arow[i]) * K + k0 + ajs[i] * 8,
                    (void*)(As + (t + i * 256) * 8));
#pragma unroll
        for (int i = 0; i < 4; i++)
            gload16(Bt + (size_t)(col0 + brow[i]) * K + k0 + bjs[i] * 8,
                    (void*)(Bs + (t + i * 256) * 8));
        __syncthreads();
#pragma unroll
        for (int kk = 0; kk < 2; kk++) {
            s16x8 af[4], bfr[2];
#pragma unroll
            for (int m = 0; m < 4; m++) af[m]  = *(const s16x8*)(As + aoff[kk][m]);
#pragma unroll
            for (int n = 0; n < 2; n++) bfr[n] = *(const s16x8*)(Bs + boff[kk][n]);
#pragma unroll
            for (int m = 0; m < 4; m++)
#pragma unroll
                for (int n = 0; n < 2; n++)
                    acc[m][n] = __builtin_amdgcn_mfma_f32_16x16x32_bf16(af[m], bfr[n], acc[m][n], 0, 0, 0);
        }
        __syncthreads();
    }
#pragma unroll
    for (int m = 0; m < 4; m++)
#pragma unroll
        for (int n = 0; n < 2; n++)
#pragma unroll
            for (int j = 0; j < 4; j++) {
                int r = row0 + m * 16 + lhi * 4 + j;
                int c = col0 + wc + n * 16 + lr;
                Co[(size_t)r * N + c] = f2bf(acc[m][n][j]);
            }
}

// ---- aggregation, C=512, HALF-CHANNEL pass (choff = 0 or 256) ----
// Working set per pass: 16384 x 512 B = 8 MB -> bucket-sweep window L2-resident.
// Per-channel summation order identical to full-width version (bit-identical out).
__global__ __launch_bounds__(256) void k_agg512h(const short* __restrict__ T,
        const int* __restrict__ offs, const int* __restrict__ cnt,
        const int* __restrict__ csr, const float* __restrict__ dinv,
        const float* __restrict__ bias, short* __restrict__ H, int choff) {
    const int w = threadIdx.x >> 6, l = threadIdx.x & 63;
    const int node = blockIdx.x * 4 + w;
    const int c0 = choff + l * 4;
    const short* base = T + c0;
    float acc[4];
    {
        s16x4 r = *(const s16x4*)(base + (size_t)node * 512);   // self loop
#pragma unroll
        for (int v = 0; v < 4; v++) acc[v] = bf2f(r[v]);
    }
    const int beg = offs[node], end = beg + cnt[node];
    int j = beg;
    for (; j + 8 <= end; j += 8) {
        int sIx[8];
#pragma unroll
        for (int q = 0; q < 8; q++) sIx[q] = csr[j + q];
        s16x4 r[8];
#pragma unroll
        for (int q = 0; q < 8; q++) r[q] = *(const s16x4*)(base + (size_t)sIx[q] * 512);
#pragma unroll
        for (int v = 0; v < 4; v++) {
            float s01 = bf2f(r[0][v]) + bf2f(r[1][v]);
            float s23 = bf2f(r[2][v]) + bf2f(r[3][v]);
            float s45 = bf2f(r[4][v]) + bf2f(r[5][v]);
            float s67 = bf2f(r[6][v]) + bf2f(r[7][v]);
            acc[v] += (s01 + s23) + (s45 + s67);
        }
    }
    for (; j + 2 <= end; j += 2) {
        int s0 = csr[j], s1 = csr[j + 1];
        s16x4 r0 = *(const s16x4*)(base + (size_t)s0 * 512);
        s16x4 r1 = *(const s16x4*)(base + (size_t)s1 * 512);
#pragma unroll
        for (int v = 0; v < 4; v++) acc[v] += bf2f(r0[v]) + bf2f(r1[v]);
    }
    for (; j < end; j++) {
        s16x4 r0 = *(const s16x4*)(base + (size_t)csr[j] * 512);
#pragma unroll
        for (int v = 0; v < 4; v++) acc[v] += bf2f(r0[v]);
    }
    const float dc = dinv[node];
    f32x4 bb = *(const f32x4*)(bias + c0);
    s16x4 outv;
#pragma unroll
    for (int v = 0; v < 4; v++) {
        float o = acc[v] * dc + bb[v];
        o = fmaxf(o, 0.f);
        o *= dc;                      // pre-scale for next layer's row norm
        outv[v] = f2bf(o);
    }
    *(s16x4*)(H + (size_t)node * 512 + c0) = outv;
}

// ---- FUSED encoder: agg256 -> hB, then part = hB @ We-slice ----
__global__ __launch_bounds__(256) void k_enc(const short* __restrict__ T,
        const int* __restrict__ offs, const int* __restrict__ cnt,
        const int* __restrict__ csr, const float* __restrict__ dinv,
        const float* __restrict__ b3, const float* __restrict__ We,
        float* __restrict__ part) {
    __shared__ float hB[8 * 512];
    __shared__ float red[32 * 128];
    const int t = threadIdx.x;
    const int w = t >> 6, l = t & 63;
    const int ln0 = blockIdx.x * 2;
    const int c0 = l * 4;
    const short* base = T + c0;
    f32x4 bb = *(const f32x4*)(b3 + c0);
    for (int p = 0; p < 4; p++) {
        const int i = w * 4 + p;
        const int b = i >> 1, lnk = i & 1;
        const int node = b * NN + ln0 + lnk;
        float acc[4];
        {
            s16x4 r = *(const s16x4*)(base + (size_t)node * 256);
#pragma unroll
            for (int v = 0; v < 4; v++) acc[v] = bf2f(r[v]);
        }
        const int beg = offs[node], end = beg + cnt[node];
        int j = beg;
        for (; j + 8 <= end; j += 8) {
            int sIx[8];
#pragma unroll
            for (int q = 0; q < 8; q++) sIx[q] = csr[j + q];
            s16x4 r[8];
#pragma unroll
            for (int q = 0; q < 8; q++) r[q] = *(const s16x4*)(base + (size_t)sIx[q] * 256);
#pragma unroll
            for (int v = 0; v < 4; v++) {
                float s01 = bf2f(r[0][v]) + bf2f(r[1][v]);
                float s23 = bf2f(r[2][v]) + bf2f(r[3][v]);
                float s45 = bf2f(r[4][v]) + bf2f(r[5][v]);
                float s67 = bf2f(r[6][v]) + bf2f(r[7][v]);
                acc[v] += (s01 + s23) + (s45 + s67);
            }
        }
        for (; j < end; j++) {
            s16x4 r0 = *(const s16x4*)(base + (size_t)csr[j] * 256);
#pragma unroll
            for (int v = 0; v < 4; v++) acc[v] += bf2f(r0[v]);
        }
        const float dc = dinv[node];
        f32x4 o;
#pragma unroll
        for (int v = 0; v < 4; v++) o[v] = acc[v] * dc + bb[v];
        *(f32x4*)(&hB[b * 512 + lnk * 256 + c0]) = o;
    }
    __syncthreads();
    const int col = (t & 127) * 4;
    const int khalf = t >> 7;
    float acc[8][4] = {};
    const float* wp = We + (size_t)(blockIdx.x * 512 + khalf * 256) * 512 + col;
    const float* hp = hB + khalf * 256;
#pragma unroll 2
    for (int k = 0; k < 256; k++) {
        f32x4 wv = *(const f32x4*)(wp + (size_t)k * 512);
        float h0 = hp[k],        h1 = hp[512 + k],  h2 = hp[1024 + k], h3v = hp[1536 + k];
        float h4 = hp[2048 + k], h5 = hp[2560 + k], h6 = hp[3072 + k], h7 = hp[3584 + k];
#pragma unroll
        for (int c = 0; c < 4; c++) {
            acc[0][c] += h0 * wv[c];
            acc[1][c] += h1 * wv[c];
            acc[2][c] += h2 * wv[c];
            acc[3][c] += h3v * wv[c];
            acc[4][c] += h4 * wv[c];
            acc[5][c] += h5 * wv[c];
            acc[6][c] += h6 * wv[c];
            acc[7][c] += h7 * wv[c];
        }
    }
    if (khalf) {
#pragma unroll
        for (int b = 0; b < 8; b++)
#pragma unroll
            for (int c = 0; c < 4; c++)
                red[(b * 4 + c) * 128 + (t - 128)] = acc[b][c];
    }
    __syncthreads();
    if (!khalf) {
#pragma unroll
        for (int b = 0; b < 8; b++) {
            f32x4 o;
#pragma unroll
            for (int c = 0; c < 4; c++) o[c] = acc[b][c] + red[(b * 4 + c) * 128 + t];
            *(f32x4*)(part + (size_t)blockIdx.x * 4096 + b * 512 + col) = o;
        }
    }
}

// ---- encoder stage 2 ----
__global__ __launch_bounds__(256) void k_zred(const float* __restrict__ part,
                                              float* __restrict__ zpart) {
    const int n = blockIdx.x * 256 + threadIdx.x;
    const int p0 = blockIdx.y * 128;
    float s = 0.f;
    for (int q = 0; q < 128; q++) s += part[(size_t)(p0 + q) * 4096 + n];
    zpart[(size_t)blockIdx.y * 4096 + n] = s;
}

// ---- decoder ----
__global__ __launch_bounds__(256) void k_dec(const float* __restrict__ zpart,
        const float* __restrict__ be, const float* __restrict__ Wd,
        const float* __restrict__ bd, float* __restrict__ out) {
    __shared__ float zs[512];
    const int b = blockIdx.x >> 3;
    const int n = ((blockIdx.x & 7) << 8) + threadIdx.x;
    for (int i = threadIdx.x; i < 512; i += 256) {
        float s = be[i];
#pragma unroll
        for (int p = 0; p < 8; p++) s += zpart[(size_t)p * 4096 + b * 512 + i];
        zs[i] = s;
    }
    __syncthreads();
    float acc = bd[n];
    for (int k = 0; k < 512; k++) acc += zs[k] * Wd[(size_t)k * 2048 + n];
    out[b * 2048 + n] = acc;
}

extern "C" void kernel_launch(void* const* d_in, const int* in_sizes, int n_in,
                              void* d_out, int out_size, void* d_ws, size_t ws_size,
                              hipStream_t stream) {
    const float* x  = (const float*)d_in[0];
    const void*  ei = d_in[1];
    const float* W1 = (const float*)d_in[4];
    const float* b1 = (const float*)d_in[5];
    const float* W2 = (const float*)d_in[6];
    const float* b2 = (const float*)d_in[7];
    const float* W3 = (const float*)d_in[8];
    const float* b3 = (const float*)d_in[9];
    const float* We = (const float*)d_in[10];
    const float* be = (const float*)d_in[11];
    const float* Wd = (const float*)d_in[12];
    const float* bd = (const float*)d_in[13];
    float* out = (float*)d_out;
    const int E = in_sizes[1] / 2;

    char* ws = (char*)d_ws;
    size_t off = 0;
    auto alloc = [&](size_t bytes) {
        void* p = ws + off;
        off = (off + bytes + 255) & ~(size_t)255;
        return p;
    };
    int*   flag   = (int*)  alloc(4);
    int*   deg    = (int*)  alloc((size_t)NT * 4);
    int*   offs   = (int*)  alloc((size_t)NT * 4);
    float* dinv   = (float*)alloc((size_t)NT * 4);
    int*   csr    = (int*)  alloc((size_t)E * 4);
    short* Wt1    = (short*)alloc((size_t)512 * 512 * 2);
    short* Wt2    = (short*)alloc((size_t)512 * 512 * 2);
    short* Wt3    = (short*)alloc((size_t)256 * 512 * 2);
    short* bufA   = (short*)alloc((size_t)NT * 512 * 2);
    short* bufB   = (short*)alloc((size_t)NT * 512 * 2);
    float* part   = (float*)alloc((size_t)1024 * 4096 * 4);
    float* zpart  = (float*)alloc((size_t)8 * 4096 * 4);
    // CSR-build temporaries alias into part (dead until k_enc writes it).
    int*   cnt16  = (int*)part;
    int*   bcur   = ((int*)part) + NT * NBKT;

    k_init<<<65, 256, 0, stream>>>(ei, flag, cnt16);
    k_count16<<<(E + 255) / 256, 256, 0, stream>>>(ei, E, flag, cnt16);
    k_deg<<<NT / 256, 256, 0, stream>>>(cnt16, deg);
    k_scan<<<1, 1024, 0, stream>>>(deg, offs, dinv);
    k_bcur<<<NT / 256, 256, 0, stream>>>(cnt16, offs, bcur);
    k_fill16<<<(E + 255) / 256, 256, 0, stream>>>(ei, E, flag, bcur, csr);

    k_convscale<<<10752, 256, 0, stream>>>(W1, W2, W3, Wt1, Wt2, Wt3, x, dinv, bufA);

    dim3 g1(256, 4);
    k_gemm<<<g1, 256, 0, stream>>>(bufA, Wt1, bufB, 512, 512);
    k_agg512h<<<NT / 4, 256, 0, stream>>>(bufB, offs, deg, csr, dinv, b1, bufA, 0);
    k_agg512h<<<NT / 4, 256, 0, stream>>>(bufB, offs, deg, csr, dinv, b1, bufA, 256);
    k_gemm<<<g1, 256, 0, stream>>>(bufA, Wt2, bufB, 512, 512);
    k_agg512h<<<NT / 4, 256, 0, stream>>>(bufB, offs, deg, csr, dinv, b2, bufA, 0);
    k_agg512h<<<NT / 4, 256, 0, stream>>>(bufB, offs, deg, csr, dinv, b2, bufA, 256);
    dim3 g3(256, 2);
    k_gemm<<<g3, 256, 0, stream>>>(bufA, Wt3, bufB, 256, 512);

    k_enc<<<1024, 256, 0, stream>>>(bufB, offs, deg, csr, dinv, b3, We, part);
    dim3 gz(16, 8);
    k_zred<<<gz, 256, 0, stream>>>(part, zpart);
    k_dec<<<64, 256, 0, stream>>>(zpart, be, Wd, bd, out);
}

// Round 13
// 476.094 us; speedup vs baseline: 1.2623x; 1.0188x over previous
//
#include <hip/hip_runtime.h>
#include <stdint.h>

#define NT 16384       // total nodes (8 * 2048)
#define NN 2048
#define NB 8
#define NBKT 16        // source buckets of 1024 nodes

typedef __attribute__((ext_vector_type(4))) float f32x4;
typedef __attribute__((ext_vector_type(8))) short s16x8;
typedef __attribute__((ext_vector_type(4))) short s16x4;

__device__ __forceinline__ float bf2f(short u) {
    unsigned v = ((unsigned)(unsigned short)u) << 16;
    return __builtin_bit_cast(float, v);
}
__device__ __forceinline__ short f2bf(float f) {
    unsigned u = __builtin_bit_cast(unsigned, f);
    u += 0x7fffu + ((u >> 16) & 1u);
    return (short)(u >> 16);
}
__device__ __forceinline__ void gload16(const void* g, void* l) {
    __builtin_amdgcn_global_load_lds(
        (const __attribute__((address_space(1))) void*)g,
        (__attribute__((address_space(3))) void*)l, 16, 0, 0);
}
__device__ __forceinline__ long long eidx(const void* ei, long long i, int is64) {
    if (is64) return ((const long long*)ei)[i];
    return (long long)((const int*)ei)[i];
}

// ---- init: blocks 0..63 zero cnt16; block 64 detects int64 vs int32 ----
__global__ void k_init(const void* ei, int* flag, int* cnt16) {
    if (blockIdx.x == 64) {
        __shared__ int bad;
        if (threadIdx.x == 0) bad = 0;
        __syncthreads();
        const long long* p = (const long long*)ei;
        for (int i = threadIdx.x; i < 2048; i += 256) {
            long long v = p[i];
            if (v < 0 || v >= NT) bad = 1;
        }
        __syncthreads();
        if (threadIdx.x == 0) *flag = bad ? 0 : 1;
    } else {
        int base = blockIdx.x * 4096 + threadIdx.x;
#pragma unroll
        for (int q = 0; q < 16; q++) cnt16[base + q * 256] = 0;
    }
}

// ---- per-(target, source-bucket) counts ----
__global__ void k_count16(const void* ei, int E, const int* flag, int* cnt16) {
    int e = blockIdx.x * 256 + threadIdx.x;
    if (e >= E) return;
    int f = *flag;
    int r = (int)eidx(ei, e, f);
    int c = (int)eidx(ei, (long long)E + e, f);
    atomicAdd(&cnt16[c * NBKT + (r >> 10)], 1);
}

// ---- deg[n] = sum over buckets ----
__global__ void k_deg(const int* __restrict__ cnt16, int* __restrict__ deg) {
    int n = blockIdx.x * 256 + threadIdx.x;
    const int* p = cnt16 + n * NBKT;
    int s = 0;
#pragma unroll
    for (int j = 0; j < NBKT; j++) s += p[j];
    deg[n] = s;
}

__global__ __launch_bounds__(1024) void k_scan(const int* __restrict__ count,
        int* __restrict__ offs, float* __restrict__ dinv) {
    __shared__ int ps[1024];
    const int t = threadIdx.x;
    const int base = t * 16;
    int loc[16];
    int s = 0;
#pragma unroll
    for (int j = 0; j < 16; j++) { loc[j] = count[base + j]; s += loc[j]; }
    ps[t] = s;
    __syncthreads();
    for (int o = 1; o < 1024; o <<= 1) {
        int v = (t >= o) ? ps[t - o] : 0;
        __syncthreads();
        ps[t] += v;
        __syncthreads();
    }
    int ex = ps[t] - s;   // exclusive prefix
#pragma unroll
    for (int j = 0; j < 16; j++) {
        offs[base + j] = ex;
        ex += loc[j];
        dinv[base + j] = rsqrtf((float)(loc[j] + 1));   // +1 self loop
    }
}

// ---- per-(node,bucket) fill cursors ----
__global__ void k_bcur(const int* __restrict__ cnt16, const int* __restrict__ offs,
                       int* __restrict__ bcur) {
    int n = blockIdx.x * 256 + threadIdx.x;
    int running = offs[n];
#pragma unroll
    for (int b = 0; b < NBKT; b++) {
        bcur[n * NBKT + b] = running;
        running += cnt16[n * NBKT + b];
    }
}

// ---- bucket-ordered CSR fill ----
__global__ void k_fill16(const void* ei, int E, const int* flag,
                         int* bcur, int* csr) {
    int e = blockIdx.x * 256 + threadIdx.x;
    if (e >= E) return;
    int f = *flag;
    int r = (int)eidx(ei, e, f);
    int c = (int)eidx(ei, (long long)E + e, f);
    int pos = atomicAdd(&bcur[c * NBKT + (r >> 10)], 1);
    csr[pos] = r;
}

// ---- fused: weight converts (blocks >= 8192) + x scale (blocks < 8192) ----
__global__ void k_convscale(const float* __restrict__ W1, const float* __restrict__ W2,
                            const float* __restrict__ W3, short* __restrict__ Wt1,
                            short* __restrict__ Wt2, short* __restrict__ Wt3,
                            const float* __restrict__ x, const float* __restrict__ dinv,
                            short* __restrict__ xs) {
    if (blockIdx.x < 8192) {
        int i = blockIdx.x * 256 + threadIdx.x;   // group of 4 floats
        f32x4 v = *(const f32x4*)(x + (size_t)i * 4);
        float d = dinv[i >> 7];
        s16x4 o;
#pragma unroll
        for (int j = 0; j < 4; j++) o[j] = f2bf(v[j] * d);
        *(s16x4*)(xs + (size_t)i * 4) = o;
    } else {
        int idx = (blockIdx.x - 8192) * 256 + threadIdx.x;
        const float* W; short* Wt; int N, base;
        if (idx < 262144)      { W = W1; Wt = Wt1; N = 512; base = idx; }
        else if (idx < 524288) { W = W2; Wt = Wt2; N = 512; base = idx - 262144; }
        else                   { W = W3; Wt = Wt3; N = 256; base = idx - 524288; }
        int k = base / N, n = base - k * N;
        Wt[(size_t)n * 512 + k] = f2bf(W[base]);
    }
}

// ---- bf16 GEMM: 64x128 tile, BK=64, T2 XOR-swizzle ----
__global__ __launch_bounds__(256, 4) void k_gemm(const short* __restrict__ A,
        const short* __restrict__ Bt, short* __restrict__ Co, int N, int K) {
    __shared__ short As[64 * 64];
    __shared__ short Bs[128 * 64];
    const int t = threadIdx.x;
    const int w = t >> 6, l = t & 63;
    const int row0 = blockIdx.x * 64;
    const int col0 = blockIdx.y * 128;
    const int lr = l & 15, lhi = l >> 4;
    const int wc = w * 32;
    f32x4 acc[4][2] = {};
    int arow[2], ajs[2], brow[4], bjs[4];
#pragma unroll
    for (int i = 0; i < 2; i++) {
        int s = t + i * 256;
        arow[i] = s >> 3; ajs[i] = (s & 7) ^ (arow[i] & 7);
    }
#pragma unroll
    for (int i = 0; i < 4; i++) {
        int s = t + i * 256;
        brow[i] = s >> 3; bjs[i] = (s & 7) ^ (brow[i] & 7);
    }
    int aoff[2][4], boff[2][2];
#pragma unroll
    for (int kk = 0; kk < 2; kk++) {
#pragma unroll
        for (int m = 0; m < 4; m++) {
            int ar = m * 16 + lr;
            aoff[kk][m] = ar * 64 + (((kk * 4 + lhi) ^ (ar & 7)) << 3);
        }
#pragma unroll
        for (int n = 0; n < 2; n++) {
            int br = wc + n * 16 + lr;
            boff[kk][n] = br * 64 + (((kk * 4 + lhi) ^ (br & 7)) << 3);
        }
    }
    for (int k0 = 0; k0 < K; k0 += 64) {
#pragma unroll
        for (int i = 0; i < 2; i++)
            gload16(A + (size_t)(row0 + arow[i]) * K + k0 + ajs[i] * 8,
                    (void*)(As + (t + i * 256) * 8));
#pragma unroll
        for (int i = 0; i < 4; i++)
            gload16(Bt + (size_t)(col0 + brow[i]) * K + k0 + bjs[i] * 8,
                    (void*)(Bs + (t + i * 256) * 8));
        __syncthreads();
#pragma unroll
        for (int kk = 0; kk < 2; kk++) {
            s16x8 af[4], bfr[2];
#pragma unroll
            for (int m = 0; m < 4; m++) af[m]  = *(const s16x8*)(As + aoff[kk][m]);
#pragma unroll
            for (int n = 0; n < 2; n++) bfr[n] = *(const s16x8*)(Bs + boff[kk][n]);
#pragma unroll
            for (int m = 0; m < 4; m++)
#pragma unroll
                for (int n = 0; n < 2; n++)
                    acc[m][n] = __builtin_amdgcn_mfma_f32_16x16x32_bf16(af[m], bfr[n], acc[m][n], 0, 0, 0);
        }
        __syncthreads();
    }
#pragma unroll
    for (int m = 0; m < 4; m++)
#pragma unroll
        for (int n = 0; n < 2; n++)
#pragma unroll
            for (int j = 0; j < 4; j++) {
                int r = row0 + m * 16 + lhi * 4 + j;
                int c = col0 + wc + n * 16 + lr;
                Co[(size_t)r * N + c] = f2bf(acc[m][n][j]);
            }
}

// ---- aggregation, C=512, both half-channel passes in ONE launch ----
// grid 8192: blocks 0..4095 do channels 0..255, blocks 4096..8191 do 256..511.
// Monotonic dispatch keeps the halves mostly time-separated (same footprint
// behavior as two launches) while dropping 2 kernel boundaries per layer.
__global__ __launch_bounds__(256) void k_agg512h(const short* __restrict__ T,
        const int* __restrict__ offs, const int* __restrict__ cnt,
        const int* __restrict__ csr, const float* __restrict__ dinv,
        const float* __restrict__ bias, short* __restrict__ H) {
    const int half = blockIdx.x >> 12;            // 0 or 1
    const int blk  = blockIdx.x & 4095;
    const int w = threadIdx.x >> 6, l = threadIdx.x & 63;
    const int node = blk * 4 + w;
    const int c0 = half * 256 + l * 4;
    const short* base = T + c0;
    float acc[4];
    {
        s16x4 r = *(const s16x4*)(base + (size_t)node * 512);   // self loop
#pragma unroll
        for (int v = 0; v < 4; v++) acc[v] = bf2f(r[v]);
    }
    const int beg = offs[node], end = beg + cnt[node];
    int j = beg;
    for (; j + 8 <= end; j += 8) {
        int sIx[8];
#pragma unroll
        for (int q = 0; q < 8; q++) sIx[q] = csr[j + q];
        s16x4 r[8];
#pragma unroll
        for (int q = 0; q < 8; q++) r[q] = *(const s16x4*)(base + (size_t)sIx[q] * 512);
#pragma unroll
        for (int v = 0; v < 4; v++) {
            float s01 = bf2f(r[0][v]) + bf2f(r[1][v]);
            float s23 = bf2f(r[2][v]) + bf2f(r[3][v]);
            float s45 = bf2f(r[4][v]) + bf2f(r[5][v]);
            float s67 = bf2f(r[6][v]) + bf2f(r[7][v]);
            acc[v] += (s01 + s23) + (s45 + s67);
        }
    }
    for (; j + 2 <= end; j += 2) {
        int s0 = csr[j], s1 = csr[j + 1];
        s16x4 r0 = *(const s16x4*)(base + (size_t)s0 * 512);
        s16x4 r1 = *(const s16x4*)(base + (size_t)s1 * 512);
#pragma unroll
        for (int v = 0; v < 4; v++) acc[v] += bf2f(r0[v]) + bf2f(r1[v]);
    }
    for (; j < end; j++) {
        s16x4 r0 = *(const s16x4*)(base + (size_t)csr[j] * 512);
#pragma unroll
        for (int v = 0; v < 4; v++) acc[v] += bf2f(r0[v]);
    }
    const float dc = dinv[node];
    f32x4 bb = *(const f32x4*)(bias + c0);
    s16x4 outv;
#pragma unroll
    for (int v = 0; v < 4; v++) {
        float o = acc[v] * dc + bb[v];
        o = fmaxf(o, 0.f);
        o *= dc;                      // pre-scale for next layer's row norm
        outv[v] = f2bf(o);
    }
    *(s16x4*)(H + (size_t)node * 512 + c0) = outv;
}

// ---- FUSED encoder: agg256 -> hB, then part = hB @ We-slice ----
__global__ __launch_bounds__(256) void k_enc(const short* __restrict__ T,
        const int* __restrict__ offs, const int* __restrict__ cnt,
        const int* __restrict__ csr, const float* __restrict__ dinv,
        const float* __restrict__ b3, const float* __restrict__ We,
        float* __restrict__ part) {
    __shared__ float hB[8 * 512];
    __shared__ float red[32 * 128];
    const int t = threadIdx.x;
    const int w = t >> 6, l = t & 63;
    const int ln0 = blockIdx.x * 2;
    const int c0 = l * 4;
    const short* base = T + c0;
    f32x4 bb = *(const f32x4*)(b3 + c0);
    for (int p = 0; p < 4; p++) {
        const int i = w * 4 + p;
        const int b = i >> 1, lnk = i & 1;
        const int node = b * NN + ln0 + lnk;
        float acc[4];
        {
            s16x4 r = *(const s16x4*)(base + (size_t)node * 256);
#pragma unroll
            for (int v = 0; v < 4; v++) acc[v] = bf2f(r[v]);
        }
        const int beg = offs[node], end = beg + cnt[node];
        int j = beg;
        for (; j + 8 <= end; j += 8) {
            int sIx[8];
#pragma unroll
            for (int q = 0; q < 8; q++) sIx[q] = csr[j + q];
            s16x4 r[8];
#pragma unroll
            for (int q = 0; q < 8; q++) r[q] = *(const s16x4*)(base + (size_t)sIx[q] * 256);
#pragma unroll
            for (int v = 0; v < 4; v++) {
                float s01 = bf2f(r[0][v]) + bf2f(r[1][v]);
                float s23 = bf2f(r[2][v]) + bf2f(r[3][v]);
                float s45 = bf2f(r[4][v]) + bf2f(r[5][v]);
                float s67 = bf2f(r[6][v]) + bf2f(r[7][v]);
                acc[v] += (s01 + s23) + (s45 + s67);
            }
        }
        for (; j < end; j++) {
            s16x4 r0 = *(const s16x4*)(base + (size_t)csr[j] * 256);
#pragma unroll
            for (int v = 0; v < 4; v++) acc[v] += bf2f(r0[v]);
        }
        const float dc = dinv[node];
        f32x4 o;
#pragma unroll
        for (int v = 0; v < 4; v++) o[v] = acc[v] * dc + bb[v];
        *(f32x4*)(&hB[b * 512 + lnk * 256 + c0]) = o;
    }
    __syncthreads();
    const int col = (t & 127) * 4;
    const int khalf = t >> 7;
    float acc[8][4] = {};
    const float* wp = We + (size_t)(blockIdx.x * 512 + khalf * 256) * 512 + col;
    const float* hp = hB + khalf * 256;
#pragma unroll 2
    for (int k = 0; k < 256; k++) {
        f32x4 wv = *(const f32x4*)(wp + (size_t)k * 512);
        float h0 = hp[k],        h1 = hp[512 + k],  h2 = hp[1024 + k], h3v = hp[1536 + k];
        float h4 = hp[2048 + k], h5 = hp[2560 + k], h6 = hp[3072 + k], h7 = hp[3584 + k];
#pragma unroll
        for (int c = 0; c < 4; c++) {
            acc[0][c] += h0 * wv[c];
            acc[1][c] += h1 * wv[c];
            acc[2][c] += h2 * wv[c];
            acc[3][c] += h3v * wv[c];
            acc[4][c] += h4 * wv[c];
            acc[5][c] += h5 * wv[c];
            acc[6][c] += h6 * wv[c];
            acc[7][c] += h7 * wv[c];
        }
    }
    if (khalf) {
#pragma unroll
        for (int b = 0; b < 8; b++)
#pragma unroll
            for (int c = 0; c < 4; c++)
                red[(b * 4 + c) * 128 + (t - 128)] = acc[b][c];
    }
    __syncthreads();
    if (!khalf) {
#pragma unroll
        for (int b = 0; b < 8; b++) {
            f32x4 o;
#pragma unroll
            for (int c = 0; c < 4; c++) o[c] = acc[b][c] + red[(b * 4 + c) * 128 + t];
            *(f32x4*)(part + (size_t)blockIdx.x * 4096 + b * 512 + col) = o;
        }
    }
}

// ---- encoder stage 2 ----
__global__ __launch_bounds__(256) void k_zred(const float* __restrict__ part,
                                              float* __restrict__ zpart) {
    const int n = blockIdx.x * 256 + threadIdx.x;
    const int p0 = blockIdx.y * 128;
    float s = 0.f;
    for (int q = 0; q < 128; q++) s += part[(size_t)(p0 + q) * 4096 + n];
    zpart[(size_t)blockIdx.y * 4096 + n] = s;
}

// ---- decoder ----
__global__ __launch_bounds__(256) void k_dec(const float* __restrict__ zpart,
        const float* __restrict__ be, const float* __restrict__ Wd,
        const float* __restrict__ bd, float* __restrict__ out) {
    __shared__ float zs[512];
    const int b = blockIdx.x >> 3;
    const int n = ((blockIdx.x & 7) << 8) + threadIdx.x;
    for (int i = threadIdx.x; i < 512; i += 256) {
        float s = be[i];
#pragma unroll
        for (int p = 0; p < 8; p++) s += zpart[(size_t)p * 4096 + b * 512 + i];
        zs[i] = s;
    }
    __syncthreads();
    float acc = bd[n];
    for (int k = 0; k < 512; k++) acc += zs[k] * Wd[(size_t)k * 2048 + n];
    out[b * 2048 + n] = acc;
}

extern "C" void kernel_launch(void* const* d_in, const int* in_sizes, int n_in,
                              void* d_out, int out_size, void* d_ws, size_t ws_size,
                              hipStream_t stream) {
    const float* x  = (const float*)d_in[0];
    const void*  ei = d_in[1];
    const float* W1 = (const float*)d_in[4];
    const float* b1 = (const float*)d_in[5];
    const float* W2 = (const float*)d_in[6];
    const float* b2 = (const float*)d_in[7];
    const float* W3 = (const float*)d_in[8];
    const float* b3 = (const float*)d_in[9];
    const float* We = (const float*)d_in[10];
    const float* be = (const float*)d_in[11];
    const float* Wd = (const float*)d_in[12];
    const float* bd = (const float*)d_in[13];
    float* out = (float*)d_out;
    const int E = in_sizes[1] / 2;

    char* ws = (char*)d_ws;
    size_t off = 0;
    auto alloc = [&](size_t bytes) {
        void* p = ws + off;
        off = (off + bytes + 255) & ~(size_t)255;
        return p;
    };
    int*   flag   = (int*)  alloc(4);
    int*   deg    = (int*)  alloc((size_t)NT * 4);
    int*   offs   = (int*)  alloc((size_t)NT * 4);
    float* dinv   = (float*)alloc((size_t)NT * 4);
    int*   csr    = (int*)  alloc((size_t)E * 4);
    short* Wt1    = (short*)alloc((size_t)512 * 512 * 2);
    short* Wt2    = (short*)alloc((size_t)512 * 512 * 2);
    short* Wt3    = (short*)alloc((size_t)256 * 512 * 2);
    short* bufA   = (short*)alloc((size_t)NT * 512 * 2);
    short* bufB   = (short*)alloc((size_t)NT * 512 * 2);
    float* part   = (float*)alloc((size_t)1024 * 4096 * 4);
    float* zpart  = (float*)alloc((size_t)8 * 4096 * 4);
    // CSR-build temporaries alias into part (dead until k_enc writes it).
    int*   cnt16  = (int*)part;
    int*   bcur   = ((int*)part) + NT * NBKT;

    k_init<<<65, 256, 0, stream>>>(ei, flag, cnt16);
    k_count16<<<(E + 255) / 256, 256, 0, stream>>>(ei, E, flag, cnt16);
    k_deg<<<NT / 256, 256, 0, stream>>>(cnt16, deg);
    k_scan<<<1, 1024, 0, stream>>>(deg, offs, dinv);
    k_bcur<<<NT / 256, 256, 0, stream>>>(cnt16, offs, bcur);
    k_fill16<<<(E + 255) / 256, 256, 0, stream>>>(ei, E, flag, bcur, csr);

    k_convscale<<<10752, 256, 0, stream>>>(W1, W2, W3, Wt1, Wt2, Wt3, x, dinv, bufA);

    dim3 g1(256, 4);
    k_gemm<<<g1, 256, 0, stream>>>(bufA, Wt1, bufB, 512, 512);
    k_agg512h<<<8192, 256, 0, stream>>>(bufB, offs, deg, csr, dinv, b1, bufA);
    k_gemm<<<g1, 256, 0, stream>>>(bufA, Wt2, bufB, 512, 512);
    k_agg512h<<<8192, 256, 0, stream>>>(bufB, offs, deg, csr, dinv, b2, bufA);
    dim3 g3(256, 2);
    k_gemm<<<g3, 256, 0, stream>>>(bufA, Wt3, bufB, 256, 512);

    k_enc<<<1024, 256, 0, stream>>>(bufB, offs, deg, csr, dinv, b3, We, part);
    dim3 gz(16, 8);
    k_zred<<<gz, 256, 0, stream>>>(part, zpart);
    k_dec<<<64, 256, 0, stream>>>(zpart, be, Wd, bd, out);
}